// Round 1
// baseline (113.745 us; speedup 1.0000x reference)
//
#include <hip/hip_runtime.h>
#include <math.h>

// Problem constants (from reference setup_inputs)
static constexpr int B_TOTAL   = 131072;
static constexpr int M_MOD     = 14;    // NB_MOD_MAX + 2
static constexpr int C_DIM     = 128;   // CONCEPT_N
static constexpr int CONCEPT_N = 128;

// ---------------------------------------------------------------------------
// Prepass: Gram matrices G[c] = W[c] (3x128) * W[c]^T  -> 6 unique floats,
// stored padded to 8 floats per concept (2x float4) in workspace.
// Only 128 concepts exist, so this removes 6/9 of the per-element FMA work
// and 2/3 of the butterfly-reduce traffic from the hot kernel.
// ---------------------------------------------------------------------------
__global__ __launch_bounds__(64) void gram_kernel(
    const float* __restrict__ W,   // (128, 3, 128)
    float*       __restrict__ Gt)  // (128, 8)
{
    const int c = blockIdx.x;      // concept id
    const int l = threadIdx.x;     // 0..63
    const float* wp = W + (size_t)c * 3 * C_DIM;
    float g00 = 0.f, g01 = 0.f, g02 = 0.f, g11 = 0.f, g12 = 0.f, g22 = 0.f;
#pragma unroll
    for (int k = 0; k < 2; ++k) {
        const int col = l + 64 * k;
        const float a0 = wp[col];
        const float a1 = wp[C_DIM + col];
        const float a2 = wp[2 * C_DIM + col];
        g00 = fmaf(a0, a0, g00); g01 = fmaf(a0, a1, g01);
        g02 = fmaf(a0, a2, g02); g11 = fmaf(a1, a1, g11);
        g12 = fmaf(a1, a2, g12); g22 = fmaf(a2, a2, g22);
    }
#pragma unroll
    for (int off = 32; off; off >>= 1) {
        g00 += __shfl_xor(g00, off, 64);
        g01 += __shfl_xor(g01, off, 64);
        g02 += __shfl_xor(g02, off, 64);
        g11 += __shfl_xor(g11, off, 64);
        g12 += __shfl_xor(g12, off, 64);
        g22 += __shfl_xor(g22, off, 64);
    }
    if (l == 0) {
        float* gp = Gt + (size_t)c * 8;
        gp[0] = g00; gp[1] = g01; gp[2] = g02; gp[3] = g11;
        gp[4] = g12; gp[5] = g22; gp[6] = 0.f; gp[7] = 0.f;
    }
}

// ---------------------------------------------------------------------------
// Main kernel. One 16-lane group per batch element, 4 elements/wave.
// argmin_j ||u - im_j||^2 = argmin_j ( P_j^T G P_j - 2 P_j . v )
// with v = W_t u (3-vec), G = W_t W_t^T; ||u||^2 is j-invariant.
// PRECOMP_G: read G from the prepass table (broadcast, L1-hit) instead of
// recomputing it per element. P loads are hoisted & branchless (clamped lane)
// so all VMEM issues in one batch -> single latency exposure per wave.
// ---------------------------------------------------------------------------
template <bool PRECOMP_G>
__global__ __launch_bounds__(256) void impact_kernel(
    const int*   __restrict__ user_ids,
    const int*   __restrict__ item_ids,
    const int*   __restrict__ concept_ids,
    const float* __restrict__ users_emb,   // (USER_N, 128)
    const float* __restrict__ item_resp,   // (ITEM_N * 14, 3)
    const float* __restrict__ W,           // (128, 3, 128)
    const int*   __restrict__ nb_mod,      // (ITEM_N,)
    const float* __restrict__ Gt,          // (128, 8) precomputed Gram
    float*       __restrict__ out)         // (B,)
{
    const int s = threadIdx.x & 15;                     // sublane in group
    const int b = blockIdx.x * 16 + (threadIdx.x >> 4); // element id

    const int uid = user_ids[b];
    const int iid = item_ids[b];
    const int cid = concept_ids[b];
    const int nb  = nb_mod[iid];

    // Hoisted, branchless P load: lane s scores modality j=s+1; clamp lanes
    // 12..15 to j=1 (their score is masked to INF below). Issuing these here
    // lets the compiler batch them with the u/W loads.
    const int jl = (s < 12) ? (s + 1) : 1;
    const float* pj = item_resp + ((size_t)iid * M_MOD + jl) * 3;
    const float p0 = pj[0], p1 = pj[1], p2 = pj[2];

    // u row: 2 x float4 per lane (256 B coalesced runs per group).
    const float4* up = (const float4*)(users_emb + (size_t)uid * C_DIM);
    const float4 uA = up[s], uB = up[s + 16];
    // W_t = W[cid]: 3 rows x 512 B.
    const float4* wp = (const float4*)(W + (size_t)cid * 3 * C_DIM);
    const float4 w0a = wp[s],      w0b = wp[16 + s];
    const float4 w1a = wp[32 + s], w1b = wp[48 + s];
    const float4 w2a = wp[64 + s], w2b = wp[80 + s];

    float v0 = 0.f, v1 = 0.f, v2 = 0.f;
    float g00, g01, g02, g11, g12, g22;

    if (PRECOMP_G) {
        // Broadcast read of the 6-entry Gram (all 16 lanes same addr, L1-hit).
        const float4* gp = (const float4*)(Gt + (size_t)cid * 8);
        const float4 gA = gp[0], gB = gp[1];
        g00 = gA.x; g01 = gA.y; g02 = gA.z; g11 = gA.w;
        g12 = gB.x; g22 = gB.y;
        // v = W_t u only: 3 FMA per column.
#define COLV(uc, a0, a1, a2)                                                   \
        do {                                                                   \
            v0 = fmaf((a0), (uc), v0);                                         \
            v1 = fmaf((a1), (uc), v1);                                         \
            v2 = fmaf((a2), (uc), v2);                                         \
        } while (0)
        COLV(uA.x, w0a.x, w1a.x, w2a.x);
        COLV(uA.y, w0a.y, w1a.y, w2a.y);
        COLV(uA.z, w0a.z, w1a.z, w2a.z);
        COLV(uA.w, w0a.w, w1a.w, w2a.w);
        COLV(uB.x, w0b.x, w1b.x, w2b.x);
        COLV(uB.y, w0b.y, w1b.y, w2b.y);
        COLV(uB.z, w0b.z, w1b.z, w2b.z);
        COLV(uB.w, w0b.w, w1b.w, w2b.w);
#undef COLV
        // Butterfly-reduce only the 3 v partials across the 16-lane group.
#pragma unroll
        for (int off = 8; off; off >>= 1) {
            v0 += __shfl_xor(v0, off, 64);
            v1 += __shfl_xor(v1, off, 64);
            v2 += __shfl_xor(v2, off, 64);
        }
    } else {
        // Fallback: inline Gram (identical to previously verified kernel).
        g00 = 0.f; g01 = 0.f; g02 = 0.f; g11 = 0.f; g12 = 0.f; g22 = 0.f;
#define COL(uc, a0, a1, a2)                                                    \
        do {                                                                   \
            v0  = fmaf((a0), (uc), v0);  v1  = fmaf((a1), (uc), v1);           \
            v2  = fmaf((a2), (uc), v2);                                        \
            g00 = fmaf((a0), (a0), g00); g01 = fmaf((a0), (a1), g01);          \
            g02 = fmaf((a0), (a2), g02); g11 = fmaf((a1), (a1), g11);          \
            g12 = fmaf((a1), (a2), g12); g22 = fmaf((a2), (a2), g22);          \
        } while (0)
        COL(uA.x, w0a.x, w1a.x, w2a.x);
        COL(uA.y, w0a.y, w1a.y, w2a.y);
        COL(uA.z, w0a.z, w1a.z, w2a.z);
        COL(uA.w, w0a.w, w1a.w, w2a.w);
        COL(uB.x, w0b.x, w1b.x, w2b.x);
        COL(uB.y, w0b.y, w1b.y, w2b.y);
        COL(uB.z, w0b.z, w1b.z, w2b.z);
        COL(uB.w, w0b.w, w1b.w, w2b.w);
#undef COL
#pragma unroll
        for (int off = 8; off; off >>= 1) {
            v0  += __shfl_xor(v0,  off, 64);
            v1  += __shfl_xor(v1,  off, 64);
            v2  += __shfl_xor(v2,  off, 64);
            g00 += __shfl_xor(g00, off, 64);
            g01 += __shfl_xor(g01, off, 64);
            g02 += __shfl_xor(g02, off, 64);
            g11 += __shfl_xor(g11, off, 64);
            g12 += __shfl_xor(g12, off, 64);
            g22 += __shfl_xor(g22, off, 64);
        }
    }

    // Lane s scores modality j = s+1 (valid iff j <= nb; nb >= 2 so j=1,2
    // always valid -> min is finite).
    float m = INFINITY;
    if (s < 12 && (s + 1) <= nb) {
        const float dot = fmaf(p0, v0, fmaf(p1, v1, p2 * v2));
        float q = p0 * p0 * g00;
        q = fmaf(p1 * p1, g11, q);
        q = fmaf(p2 * p2, g22, q);
        q = fmaf(2.0f * p0 * p1, g01, q);
        q = fmaf(2.0f * p0 * p2, g02, q);
        q = fmaf(2.0f * p1 * p2, g12, q);
        m = fmaf(-2.0f, dot, q);
    }
    // Group-wide min, then first-set-bit for jnp.argmin's lowest-index tie rule.
    float bm = m;
#pragma unroll
    for (int off = 8; off; off >>= 1)
        bm = fminf(bm, __shfl_xor(bm, off, 64));
    const unsigned long long mask = __ballot(m == bm);
    if (s == 0) {
        const int group = (threadIdx.x >> 4) & 3;
        const unsigned slice = (unsigned)((mask >> (group * 16)) & 0xffffu);
        const int jm1 = __builtin_ctz(slice);   // lane s ↔ j=s+1, so ctz = j-1
        out[b] = (float)jm1 / (float)(nb - 1) + 1.0f;
    }
}

extern "C" void kernel_launch(void* const* d_in, const int* in_sizes, int n_in,
                              void* d_out, int out_size, void* d_ws, size_t ws_size,
                              hipStream_t stream) {
    const int*   user_ids    = (const int*)d_in[0];
    const int*   item_ids    = (const int*)d_in[1];
    const int*   concept_ids = (const int*)d_in[2];
    const float* users_emb   = (const float*)d_in[3];
    const float* item_resp   = (const float*)d_in[4];
    const float* W           = (const float*)d_in[5];
    // d_in[6] = mask: unused — validity recomputed from nb_modalities.
    const int*   nb_mod      = (const int*)d_in[7];
    float*       out         = (float*)d_out;

    const size_t gram_bytes = (size_t)CONCEPT_N * 8 * sizeof(float); // 4 KB

    dim3 grid(B_TOTAL / 16), block(256);
    if (d_ws != nullptr && ws_size >= gram_bytes) {
        float* Gt = (float*)d_ws;
        gram_kernel<<<dim3(CONCEPT_N), dim3(64), 0, stream>>>(W, Gt);
        impact_kernel<true><<<grid, block, 0, stream>>>(
            user_ids, item_ids, concept_ids, users_emb, item_resp, W, nb_mod,
            Gt, out);
    } else {
        impact_kernel<false><<<grid, block, 0, stream>>>(
            user_ids, item_ids, concept_ids, users_emb, item_resp, W, nb_mod,
            nullptr, out);
    }
}

// Round 2
// 113.086 us; speedup vs baseline: 1.0058x; 1.0058x over previous
//
#include <hip/hip_runtime.h>
#include <math.h>

// Problem constants (from reference setup_inputs)
static constexpr int B_TOTAL = 131072;
static constexpr int M_MOD   = 14;    // NB_MOD_MAX + 2
static constexpr int C_DIM   = 128;   // CONCEPT_N

// One 16-lane group per TWO batch elements (loads for both issued up front,
// compute back-to-back) -> 8 elements in flight per wave instead of 4.
// The harness poison-fill (256 MB, seen in rocprof) cold-starts L2/L3 every
// iteration, so the u/P gathers are HBM-latency gathers; doubling the number
// of in-flight elements per wave is the latency-hiding lever.
//
// Algebra (unchanged, verified absmax=0): argmin_j ||u - im_j||^2
//   = argmin_j ( P_j^T G P_j - 2 P_j . v ),  v = W_t u,  G = W_t W_t^T.
// Lane s owns 8 concept columns {4s..4s+3, 64+4s..64+4s+3}; v and G are
// butterfly-reduced over the 16-lane group; lane s scores modality j=s+1;
// fminf butterfly + ballot/ctz picks the first-index argmin (jnp tiebreak).
__global__ __launch_bounds__(256, 4) void impact_kernel(
    const int*   __restrict__ user_ids,
    const int*   __restrict__ item_ids,
    const int*   __restrict__ concept_ids,
    const float* __restrict__ users_emb,   // (USER_N, 128)
    const float* __restrict__ item_resp,   // (ITEM_N * 14, 3)
    const float* __restrict__ W,           // (128, 3, 128)
    const int*   __restrict__ nb_mod,      // (ITEM_N,)
    float*       __restrict__ out)         // (B,)
{
    const int s = threadIdx.x & 15;        // sublane in group
    const int g = threadIdx.x >> 4;        // group in block (0..15)
    const int b0 = blockIdx.x * 32 + g * 2;
    const int b1 = b0 + 1;

    // ---- Load phase: everything for BOTH elements issued before any compute.
    const int uid0 = user_ids[b0],    uid1 = user_ids[b1];
    const int iid0 = item_ids[b0],    iid1 = item_ids[b1];
    const int cid0 = concept_ids[b0], cid1 = concept_ids[b1];
    const int nb0  = nb_mod[iid0],    nb1  = nb_mod[iid1];

    // Branchless P loads: lane s scores modality j=s+1; lanes 12..15 clamp to
    // j=1 (their score is masked to INF below).
    const int jl = (s < 12) ? (s + 1) : 1;
    const float* pj0 = item_resp + ((size_t)iid0 * M_MOD + jl) * 3;
    const float* pj1 = item_resp + ((size_t)iid1 * M_MOD + jl) * 3;
    const float p00 = pj0[0], p01 = pj0[1], p02 = pj0[2];
    const float p10 = pj1[0], p11 = pj1[1], p12 = pj1[2];

    // u rows: 2 x float4 per lane per element (512 B coalesced per element).
    const float4* up0 = (const float4*)(users_emb + (size_t)uid0 * C_DIM);
    const float4* up1 = (const float4*)(users_emb + (size_t)uid1 * C_DIM);
    const float4 u0A = up0[s], u0B = up0[s + 16];
    const float4 u1A = up1[s], u1B = up1[s + 16];

    // W_t rows: 3 x 512 B per element (L2-resident table, 196 KB).
    const float4* wp0 = (const float4*)(W + (size_t)cid0 * 3 * C_DIM);
    const float4* wp1 = (const float4*)(W + (size_t)cid1 * 3 * C_DIM);
    const float4 x0a = wp0[s],      x0b = wp0[16 + s];
    const float4 x1a = wp0[32 + s], x1b = wp0[48 + s];
    const float4 x2a = wp0[64 + s], x2b = wp0[80 + s];
    const float4 y0a = wp1[s],      y0b = wp1[16 + s];
    const float4 y1a = wp1[32 + s], y1b = wp1[48 + s];
    const float4 y2a = wp1[64 + s], y2b = wp1[80 + s];

#define COL(uc, a0, a1, a2)                                                    \
    do {                                                                       \
        v0  = fmaf((a0), (uc), v0);  v1  = fmaf((a1), (uc), v1);               \
        v2  = fmaf((a2), (uc), v2);                                            \
        g00 = fmaf((a0), (a0), g00); g01 = fmaf((a0), (a1), g01);              \
        g02 = fmaf((a0), (a2), g02); g11 = fmaf((a1), (a1), g11);              \
        g12 = fmaf((a1), (a2), g12); g22 = fmaf((a2), (a2), g22);              \
    } while (0)

#define REDUCE9()                                                              \
    _Pragma("unroll")                                                          \
    for (int off = 8; off; off >>= 1) {                                        \
        v0  += __shfl_xor(v0,  off, 64);                                       \
        v1  += __shfl_xor(v1,  off, 64);                                       \
        v2  += __shfl_xor(v2,  off, 64);                                       \
        g00 += __shfl_xor(g00, off, 64);                                       \
        g01 += __shfl_xor(g01, off, 64);                                       \
        g02 += __shfl_xor(g02, off, 64);                                       \
        g11 += __shfl_xor(g11, off, 64);                                       \
        g12 += __shfl_xor(g12, off, 64);                                       \
        g22 += __shfl_xor(g22, off, 64);                                       \
    }

#define SCORE_AND_WRITE(P0, P1, P2, NB, BIDX)                                  \
    do {                                                                       \
        float m = INFINITY;                                                    \
        if (s < 12 && (s + 1) <= (NB)) {                                       \
            const float dot = fmaf((P0), v0, fmaf((P1), v1, (P2) * v2));       \
            float q = (P0) * (P0) * g00;                                       \
            q = fmaf((P1) * (P1), g11, q);                                     \
            q = fmaf((P2) * (P2), g22, q);                                     \
            q = fmaf(2.0f * (P0) * (P1), g01, q);                              \
            q = fmaf(2.0f * (P0) * (P2), g02, q);                              \
            q = fmaf(2.0f * (P1) * (P2), g12, q);                              \
            m = fmaf(-2.0f, dot, q);                                           \
        }                                                                      \
        float bm = m;                                                          \
        _Pragma("unroll")                                                      \
        for (int off = 8; off; off >>= 1)                                      \
            bm = fminf(bm, __shfl_xor(bm, off, 64));                           \
        const unsigned long long mask = __ballot(m == bm);                     \
        if (s == 0) {                                                          \
            const int grp = g & 3;                                             \
            const unsigned slice = (unsigned)((mask >> (grp * 16)) & 0xffffu); \
            const int jm1 = __builtin_ctz(slice);                              \
            out[BIDX] = (float)jm1 / (float)((NB) - 1) + 1.0f;                 \
        }                                                                      \
    } while (0)

    // ---- Element 0 ----
    {
        float v0 = 0.f, v1 = 0.f, v2 = 0.f;
        float g00 = 0.f, g01 = 0.f, g02 = 0.f, g11 = 0.f, g12 = 0.f, g22 = 0.f;
        COL(u0A.x, x0a.x, x1a.x, x2a.x);
        COL(u0A.y, x0a.y, x1a.y, x2a.y);
        COL(u0A.z, x0a.z, x1a.z, x2a.z);
        COL(u0A.w, x0a.w, x1a.w, x2a.w);
        COL(u0B.x, x0b.x, x1b.x, x2b.x);
        COL(u0B.y, x0b.y, x1b.y, x2b.y);
        COL(u0B.z, x0b.z, x1b.z, x2b.z);
        COL(u0B.w, x0b.w, x1b.w, x2b.w);
        REDUCE9();
        SCORE_AND_WRITE(p00, p01, p02, nb0, b0);
    }

    // ---- Element 1 ----
    {
        float v0 = 0.f, v1 = 0.f, v2 = 0.f;
        float g00 = 0.f, g01 = 0.f, g02 = 0.f, g11 = 0.f, g12 = 0.f, g22 = 0.f;
        COL(u1A.x, y0a.x, y1a.x, y2a.x);
        COL(u1A.y, y0a.y, y1a.y, y2a.y);
        COL(u1A.z, y0a.z, y1a.z, y2a.z);
        COL(u1A.w, y0a.w, y1a.w, y2a.w);
        COL(u1B.x, y0b.x, y1b.x, y2b.x);
        COL(u1B.y, y0b.y, y1b.y, y2b.y);
        COL(u1B.z, y0b.z, y1b.z, y2b.z);
        COL(u1B.w, y0b.w, y1b.w, y2b.w);
        REDUCE9();
        SCORE_AND_WRITE(p10, p11, p12, nb1, b1);
    }

#undef COL
#undef REDUCE9
#undef SCORE_AND_WRITE
}

extern "C" void kernel_launch(void* const* d_in, const int* in_sizes, int n_in,
                              void* d_out, int out_size, void* d_ws, size_t ws_size,
                              hipStream_t stream) {
    const int*   user_ids    = (const int*)d_in[0];
    const int*   item_ids    = (const int*)d_in[1];
    const int*   concept_ids = (const int*)d_in[2];
    const float* users_emb   = (const float*)d_in[3];
    const float* item_resp   = (const float*)d_in[4];
    const float* W           = (const float*)d_in[5];
    // d_in[6] = mask: unused — validity recomputed from nb_modalities.
    const int*   nb_mod      = (const int*)d_in[7];
    float*       out         = (float*)d_out;

    dim3 grid(B_TOTAL / 32), block(256);
    impact_kernel<<<grid, block, 0, stream>>>(user_ids, item_ids, concept_ids,
                                              users_emb, item_resp, W, nb_mod, out);
}